// Round 5
// baseline (1211.110 us; speedup 1.0000x reference)
//
#include <hip/hip_runtime.h>
#include <hip/hip_bf16.h>

#define H 192
#define HH (192*192)
#define NLAYER 13

typedef unsigned short u16;
typedef unsigned int u32;

typedef __attribute__((ext_vector_type(8))) short short8;
typedef __attribute__((ext_vector_type(4))) float floatx4;

__device__ __forceinline__ u16 f2bf(float f) {
    u32 u = __float_as_uint(f);
    u32 r = (u + 0x7FFFu + ((u >> 16) & 1u)) >> 16;   // RNE
    return (u16)r;
}
__device__ __forceinline__ float bf2f(u16 h) {
    return __uint_as_float(((u32)h) << 16);
}

// ---------------- CSR construction (scan-free) ----------------

__global__ void hist_kernel(const int* __restrict__ dst, int* __restrict__ counts, int E) {
    int e = blockIdx.x * blockDim.x + threadIdx.x;
    if (e < E) atomicAdd(&counts[dst[e]], 1);
}

// base[v] via atomicAdd on a global counter: no prefix scan needed (CSR rows
// may live anywhere; spmm only needs beg/cnt). Order varies run-to-run; only
// fp32 summation order changes (noise << threshold).
__global__ void alloc_kernel(const int* __restrict__ counts, int* __restrict__ rbeg,
                             int* __restrict__ rcnt, int* __restrict__ cursor,
                             int* __restrict__ total, int Nv) {
    int v = blockIdx.x * blockDim.x + threadIdx.x;
    if (v >= Nv) return;
    int c = counts[v];
    int base = atomicAdd(total, c);
    rbeg[v] = base;
    rcnt[v] = c;
    cursor[v] = base;
}

__global__ void scatter_kernel(const int* __restrict__ src, const int* __restrict__ dst,
                               const float* __restrict__ w, int* __restrict__ cursor,
                               int2* __restrict__ ce, int E) {
    int e = blockIdx.x * blockDim.x + threadIdx.x;
    if (e < E) {
        int p = atomicAdd(&cursor[dst[e]], 1);
        int2 pk; pk.x = src[e]; pk.y = __float_as_int(w[e]);
        ce[p] = pk;
    }
}

// ---------------- Weight prep: Wt_hi/Wt_lo[l][n][k] = split(W[l][k][n]) ----------------

__global__ void wprep_kernel(const float* __restrict__ W, u16* __restrict__ Wt_hi,
                             u16* __restrict__ Wt_lo, int total) {
    int idx = blockIdx.x * blockDim.x + threadIdx.x;
    if (idx >= total) return;
    int l = idx / HH;
    int rem = idx - l * HH;
    int k = rem / H;
    int n = rem - k * H;
    float v = W[(size_t)l * HH + (size_t)k * H + n];
    u16 hi = f2bf(v);
    float res = v - bf2f(hi);
    u16 lo = f2bf(res);
    size_t o = (size_t)l * HH + (size_t)n * H + k;
    Wt_hi[o] = hi;
    Wt_lo[o] = lo;
}

// ---------------- features fp32 -> bf16 ----------------

__global__ void conv_kernel(const float* __restrict__ in, u16* __restrict__ out, int total4) {
    int idx = blockIdx.x * blockDim.x + threadIdx.x;
    if (idx >= total4) return;
    float4 v = ((const float4*)in)[idx];
    ushort4 p;
    p.x = f2bf(v.x); p.y = f2bf(v.y); p.z = f2bf(v.z); p.w = f2bf(v.w);
    ((ushort4*)out)[idx] = p;
}

// ---------------- SpMM (pure aggregation): out_bf = adj @ S   ----------------
// grid = VC blocks (all co-resident); each block loops cg=0,1,2 internally so
// every resident block works the SAME 3.2MB column slice at the same time
// (per-XCD L2 resident). 8 lanes/vertex, 8 cols/lane (one uint4/edge/lane).

__device__ __forceinline__ void fma8(float acc[8], uint4 q, float w) {
    u32 u[4] = {q.x, q.y, q.z, q.w};
    #pragma unroll
    for (int i = 0; i < 4; i++) {
        float lo = __uint_as_float(u[i] << 16);
        float hi = __uint_as_float(u[i] & 0xFFFF0000u);
        acc[2*i]     += w * lo;
        acc[2*i + 1] += w * hi;
    }
}

__global__ __launch_bounds__(192) void spmm_raw(
    const u16* __restrict__ S, const int* __restrict__ rbeg, const int* __restrict__ rcnt,
    const int2* __restrict__ ce, u16* __restrict__ out, int Nv)
{
    int tid = threadIdx.x;               // 0..191
    int g = tid >> 3;                    // vertex 0..23
    int l = tid & 7;                     // lane within vertex
    int v = blockIdx.x * 24 + g;
    if (v >= Nv) return;
    int beg = rbeg[v], cnt = rcnt[v];
    const int2* cep = ce + beg;
    #pragma unroll
    for (int cg = 0; cg < 3; cg++) {
        int c0 = cg * 64 + l * 8;
        const u16* Sc = S + c0;
        float acc[8] = {};
        int e = 0;
        for (; e + 1 < cnt; e += 2) {
            int2 p0 = cep[e], p1 = cep[e + 1];
            uint4 q0 = *(const uint4*)(Sc + (size_t)p0.x * H);
            uint4 q1 = *(const uint4*)(Sc + (size_t)p1.x * H);
            fma8(acc, q0, __int_as_float(p0.y));
            fma8(acc, q1, __int_as_float(p1.y));
        }
        if (e < cnt) {
            int2 p0 = cep[e];
            uint4 q0 = *(const uint4*)(Sc + (size_t)p0.x * H);
            fma8(acc, q0, __int_as_float(p0.y));
        }
        size_t idx = (size_t)v * H + c0;
        ushort4 o0, o1;
        o0.x = f2bf(acc[0]); o0.y = f2bf(acc[1]); o0.z = f2bf(acc[2]); o0.w = f2bf(acc[3]);
        o1.x = f2bf(acc[4]); o1.y = f2bf(acc[5]); o1.z = f2bf(acc[6]); o1.w = f2bf(acc[7]);
        *(ushort4*)&out[idx] = o0;
        *(ushort4*)&out[idx + 4] = o1;
    }
}

// ---------------- MFMA GEMM with fused epilogue ----------------
// C = relu(A @ (W_hi+W_lo) + b), then
// mode 0: out_bf = bf16(C)
// mode 1: f = (resid + C)*0.5 ; out_f = f ; out_bf = bf16(f)

__global__ __launch_bounds__(256) void gemm_fused(
    const u16* __restrict__ A, const u16* __restrict__ Wt_hi, const u16* __restrict__ Wt_lo,
    const float* __restrict__ bias, u16* __restrict__ out_bf, float* __restrict__ out_f,
    const float* __restrict__ resid, int mode, int M)
{
    int wave = threadIdx.x >> 6;
    int lane = threadIdx.x & 63;
    int gw = blockIdx.x * 4 + wave;
    int chunk = gw >> 1;
    int half = gw & 1;
    int rm = chunk * 16;
    if (rm >= M) return;
    int col = lane & 15;
    int quad = lane >> 4;

    int arow = rm + col;
    if (arow >= M) arow = M - 1;
    const u16* Ap = A + (size_t)arow * H + quad * 8;
    short8 a[6];
    #pragma unroll
    for (int k = 0; k < 6; k++) a[k] = *(const short8*)(Ap + k * 32);

    floatx4 acc[6];
    int nb = half * 6;
    #pragma unroll
    for (int nt = 0; nt < 6; nt++) {
        int n = (nb + nt) * 16 + col;
        const u16* Bh = Wt_hi + (size_t)n * H + quad * 8;
        const u16* Bl = Wt_lo + (size_t)n * H + quad * 8;
        floatx4 c = {0.f, 0.f, 0.f, 0.f};
        #pragma unroll
        for (int k = 0; k < 6; k++) {
            short8 bh = *(const short8*)(Bh + k * 32);
            short8 bl = *(const short8*)(Bl + k * 32);
            c = __builtin_amdgcn_mfma_f32_16x16x32_bf16(a[k], bh, c, 0, 0, 0);
            c = __builtin_amdgcn_mfma_f32_16x16x32_bf16(a[k], bl, c, 0, 0, 0);
        }
        acc[nt] = c;
    }
    #pragma unroll
    for (int nt = 0; nt < 6; nt++) {
        int n = (nb + nt) * 16 + col;
        float b = bias[n];
        #pragma unroll
        for (int r = 0; r < 4; r++) {
            int row = rm + quad * 4 + r;
            if (row < M) {
                float z = fmaxf(acc[nt][r] + b, 0.f);
                size_t o = (size_t)row * H + n;
                if (mode == 1) {
                    float f = (resid[o] + z) * 0.5f;
                    out_f[o] = f;
                    out_bf[o] = f2bf(f);
                } else {
                    out_bf[o] = f2bf(z);
                }
            }
        }
    }
}

// ---------------- Output head: coords = (adj@feats) @ W_out + b_out ----------------

__global__ void head_kernel(const u16* __restrict__ A, const float* __restrict__ W,
                            const float* __restrict__ b, float* __restrict__ coords, int M) {
    int row = blockIdx.x * blockDim.x + threadIdx.x;
    if (row >= M) return;
    float a0 = b[0], a1 = b[1], a2 = b[2];
    const u16* Ar = A + (size_t)row * H;
    for (int k = 0; k < H; k++) {
        float x = bf2f(Ar[k]);
        a0 += x * W[k * 3 + 0];
        a1 += x * W[k * 3 + 1];
        a2 += x * W[k * 3 + 2];
    }
    coords[row * 3 + 0] = a0;
    coords[row * 3 + 1] = a1;
    coords[row * 3 + 2] = a2;
}

// ---------------- Launch ----------------

extern "C" void kernel_launch(void* const* d_in, const int* in_sizes, int n_in,
                              void* d_out, int out_size, void* d_ws, size_t ws_size,
                              hipStream_t stream) {
    const float* features = (const float*)d_in[0];
    const int*   edge_src = (const int*)d_in[1];
    const int*   edge_dst = (const int*)d_in[2];
    const float* edge_w   = (const float*)d_in[3];
    const float* Ws       = (const float*)d_in[4];
    const float* bs       = (const float*)d_in[5];
    const float* W_out    = (const float*)d_in[6];
    const float* b_out    = (const float*)d_in[7];

    const int N = in_sizes[0] / H;
    const int E = in_sizes[1];

    float* coords = (float*)d_out;
    float* feats  = coords + (size_t)N * 3;   // fp32 feats output/accumulator

    char* wptr = (char*)d_ws;
    u16* xbuf_bf  = (u16*)wptr;   wptr += (size_t)N * H * sizeof(u16);
    u16* sup      = (u16*)wptr;   wptr += (size_t)N * H * sizeof(u16);
    u16* feats_bf = (u16*)wptr;   wptr += (size_t)N * H * sizeof(u16);
    u16* Wt_hi    = (u16*)wptr;   wptr += (size_t)NLAYER * HH * sizeof(u16);
    u16* Wt_lo    = (u16*)wptr;   wptr += (size_t)NLAYER * HH * sizeof(u16);
    int* counts   = (int*)wptr;   wptr += (size_t)N * sizeof(int);
    int* total    = (int*)wptr;   wptr += 4;                      // contiguous with counts
    int* rbeg     = (int*)wptr;   wptr += (size_t)N * sizeof(int);
    int* rcnt     = (int*)wptr;   wptr += (size_t)N * sizeof(int);
    int* cursor   = (int*)wptr;   wptr += (size_t)N * sizeof(int);
    int2* ce      = (int2*)wptr;  wptr += (size_t)E * sizeof(int2);

    // --- build CSR (dst-indexed, scan-free) ---
    hipMemsetAsync(counts, 0, (size_t)(N + 1) * sizeof(int), stream);  // counts + total
    hist_kernel<<<(E + 255) / 256, 256, 0, stream>>>(edge_dst, counts, E);
    alloc_kernel<<<(N + 255) / 256, 256, 0, stream>>>(counts, rbeg, rcnt, cursor, total, N);
    scatter_kernel<<<(E + 255) / 256, 256, 0, stream>>>(edge_src, edge_dst, edge_w,
                                                        cursor, ce, E);

    // --- weight split/transpose + feature conversion ---
    int wtotal = NLAYER * HH;
    wprep_kernel<<<(wtotal + 255) / 256, 256, 0, stream>>>(Ws, Wt_hi, Wt_lo, wtotal);
    int c4 = N * H / 4;
    conv_kernel<<<(c4 + 255) / 256, 256, 0, stream>>>(features, xbuf_bf, c4);

    int gwaves = 2 * ((N + 15) / 16);
    int gblocks = (gwaves + 3) / 4;
    int VC = (N + 23) / 24;

    // L0: agg = adj@f ; x0 = relu(agg W0 + b0)        [xbuf_bf holds f_bf, then x0_bf]
    spmm_raw<<<VC, 192, 0, stream>>>(xbuf_bf, rbeg, rcnt, ce, sup, N);
    gemm_fused<<<gblocks, 256, 0, stream>>>(sup, Wt_hi + 0 * HH, Wt_lo + 0 * HH, bs + 0 * H,
                                            xbuf_bf, nullptr, nullptr, 0, N);
    // L1: agg = adj@x0 ; feats = (features + relu(agg W1 + b1))/2
    spmm_raw<<<VC, 192, 0, stream>>>(xbuf_bf, rbeg, rcnt, ce, sup, N);
    gemm_fused<<<gblocks, 256, 0, stream>>>(sup, Wt_hi + 1 * HH, Wt_lo + 1 * HH, bs + 1 * H,
                                            feats_bf, feats, features, 1, N);

    // blocks 2-6
    for (int i = 2; i < 12; i += 2) {
        spmm_raw<<<VC, 192, 0, stream>>>(feats_bf, rbeg, rcnt, ce, sup, N);
        gemm_fused<<<gblocks, 256, 0, stream>>>(sup, Wt_hi + (size_t)i * HH, Wt_lo + (size_t)i * HH,
                                                bs + (size_t)i * H, xbuf_bf, nullptr, nullptr, 0, N);
        spmm_raw<<<VC, 192, 0, stream>>>(xbuf_bf, rbeg, rcnt, ce, sup, N);
        gemm_fused<<<gblocks, 256, 0, stream>>>(sup, Wt_hi + (size_t)(i+1) * HH, Wt_lo + (size_t)(i+1) * HH,
                                                bs + (size_t)(i+1) * H, feats_bf, feats, feats, 1, N);
    }

    // gc13
    spmm_raw<<<VC, 192, 0, stream>>>(feats_bf, rbeg, rcnt, ce, sup, N);
    gemm_fused<<<gblocks, 256, 0, stream>>>(sup, Wt_hi + 12 * (size_t)HH, Wt_lo + 12 * (size_t)HH,
                                            bs + 12 * H, feats_bf, feats, feats, 1, N);

    // head: coords = (adj@feats) W_out + b_out
    spmm_raw<<<VC, 192, 0, stream>>>(feats_bf, rbeg, rcnt, ce, sup, N);
    head_kernel<<<(N + 255) / 256, 256, 0, stream>>>(sup, W_out, b_out, coords, N);
}

// Round 6
// 1060.987 us; speedup vs baseline: 1.1415x; 1.1415x over previous
//
#include <hip/hip_runtime.h>
#include <hip/hip_bf16.h>

#define H 192
#define HH (192*192)
#define NLAYER 13

typedef unsigned short u16;
typedef unsigned int u32;

typedef __attribute__((ext_vector_type(8))) short short8;
typedef __attribute__((ext_vector_type(4))) float floatx4;

__device__ __forceinline__ u16 f2bf(float f) {
    u32 u = __float_as_uint(f);
    u32 r = (u + 0x7FFFu + ((u >> 16) & 1u)) >> 16;   // RNE
    return (u16)r;
}
__device__ __forceinline__ float bf2f(u16 h) {
    return __uint_as_float(((u32)h) << 16);
}
__device__ __forceinline__ u32 pack2(float lo, float hi) {
    return (u32)f2bf(lo) | ((u32)f2bf(hi) << 16);
}

// ---------------- CSR construction (scan-free) ----------------

__global__ void hist_kernel(const int* __restrict__ dst, int* __restrict__ counts, int E) {
    int e = blockIdx.x * blockDim.x + threadIdx.x;
    if (e < E) atomicAdd(&counts[dst[e]], 1);
}

__global__ void alloc_kernel(const int* __restrict__ counts, int* __restrict__ rbeg,
                             int* __restrict__ rcnt, int* __restrict__ cursor,
                             int* __restrict__ total, int Nv) {
    int v = blockIdx.x * blockDim.x + threadIdx.x;
    if (v >= Nv) return;
    int c = counts[v];
    int base = atomicAdd(total, c);
    rbeg[v] = base;
    rcnt[v] = c;
    cursor[v] = base;
}

__global__ void scatter_kernel(const int* __restrict__ src, const int* __restrict__ dst,
                               const float* __restrict__ w, int* __restrict__ cursor,
                               int2* __restrict__ ce, int E) {
    int e = blockIdx.x * blockDim.x + threadIdx.x;
    if (e < E) {
        int p = atomicAdd(&cursor[dst[e]], 1);
        int2 pk; pk.x = src[e]; pk.y = __float_as_int(w[e]);
        ce[p] = pk;
    }
}

// ---------------- Weight prep: Wt_hi/Wt_lo[l][n][k] = split(W[l][k][n]) ----------------

__global__ void wprep_kernel(const float* __restrict__ W, u16* __restrict__ Wt_hi,
                             u16* __restrict__ Wt_lo, int total) {
    int idx = blockIdx.x * blockDim.x + threadIdx.x;
    if (idx >= total) return;
    int l = idx / HH;
    int rem = idx - l * HH;
    int k = rem / H;
    int n = rem - k * H;
    float v = W[(size_t)l * HH + (size_t)k * H + n];
    u16 hi = f2bf(v);
    float res = v - bf2f(hi);
    u16 lo = f2bf(res);
    size_t o = (size_t)l * HH + (size_t)n * H + k;
    Wt_hi[o] = hi;
    Wt_lo[o] = lo;
}

// ---------------- features fp32 -> bf16 ----------------

__global__ void conv_kernel(const float* __restrict__ in, u16* __restrict__ out, int total4) {
    int idx = blockIdx.x * blockDim.x + threadIdx.x;
    if (idx >= total4) return;
    float4 v = ((const float4*)in)[idx];
    ushort4 p;
    p.x = f2bf(v.x); p.y = f2bf(v.y); p.z = f2bf(v.z); p.w = f2bf(v.w);
    ((ushort4*)out)[idx] = p;
}

// ---------------- SpMM (pure aggregation): out_bf = adj @ S ----------------
// Block loops cg=0,1,2 internally (phase-aligned 3.2MB slice per XCD L2).
// 8 lanes/vertex, 8 cols/lane; 4x edge unroll for MLP.

__device__ __forceinline__ void fma8(float acc[8], uint4 q, float w) {
    u32 u[4] = {q.x, q.y, q.z, q.w};
    #pragma unroll
    for (int i = 0; i < 4; i++) {
        float lo = __uint_as_float(u[i] << 16);
        float hi = __uint_as_float(u[i] & 0xFFFF0000u);
        acc[2*i]     += w * lo;
        acc[2*i + 1] += w * hi;
    }
}

__global__ __launch_bounds__(192) void spmm_raw(
    const u16* __restrict__ S, const int* __restrict__ rbeg, const int* __restrict__ rcnt,
    const int2* __restrict__ ce, u16* __restrict__ out, int Nv)
{
    int tid = threadIdx.x;               // 0..191
    int g = tid >> 3;                    // vertex 0..23
    int l = tid & 7;                     // lane within vertex
    int v = blockIdx.x * 24 + g;
    if (v >= Nv) return;
    int beg = rbeg[v], cnt = rcnt[v];
    const int2* cep = ce + beg;
    #pragma unroll
    for (int cg = 0; cg < 3; cg++) {
        int c0 = cg * 64 + l * 8;
        const u16* Sc = S + c0;
        float acc[8] = {};
        int e = 0;
        for (; e + 3 < cnt; e += 4) {
            int2 p0 = cep[e], p1 = cep[e + 1], p2 = cep[e + 2], p3 = cep[e + 3];
            uint4 q0 = *(const uint4*)(Sc + (size_t)p0.x * H);
            uint4 q1 = *(const uint4*)(Sc + (size_t)p1.x * H);
            uint4 q2 = *(const uint4*)(Sc + (size_t)p2.x * H);
            uint4 q3 = *(const uint4*)(Sc + (size_t)p3.x * H);
            fma8(acc, q0, __int_as_float(p0.y));
            fma8(acc, q1, __int_as_float(p1.y));
            fma8(acc, q2, __int_as_float(p2.y));
            fma8(acc, q3, __int_as_float(p3.y));
        }
        for (; e < cnt; e++) {
            int2 p0 = cep[e];
            uint4 q0 = *(const uint4*)(Sc + (size_t)p0.x * H);
            fma8(acc, q0, __int_as_float(p0.y));
        }
        size_t idx = (size_t)v * H + c0;
        ushort4 o0, o1;
        o0.x = f2bf(acc[0]); o0.y = f2bf(acc[1]); o0.z = f2bf(acc[2]); o0.w = f2bf(acc[3]);
        o1.x = f2bf(acc[4]); o1.y = f2bf(acc[5]); o1.z = f2bf(acc[6]); o1.w = f2bf(acc[7]);
        *(ushort4*)&out[idx] = o0;
        *(ushort4*)&out[idx + 4] = o1;
    }
}

// ---------------- MFMA GEMM with LDS-staged coalesced epilogue ----------------
// Block = 4 waves = 2 row-chunks of 16 (32 rows). MFMA accumulates; acc goes
// through LDS; phase 2 re-partitions to row-contiguous 24-col segments so all
// global epilogue traffic is float4/uint4 coalesced.
// mode 0: out_bf = bf16(relu(C + b))
// mode 1: f = (resid + relu(C + b))*0.5 ; out_f = f ; out_bf = bf16(f)

__global__ __launch_bounds__(256) void gemm_fused(
    const u16* __restrict__ A, const u16* __restrict__ Wt_hi, const u16* __restrict__ Wt_lo,
    const float* __restrict__ bias, u16* __restrict__ out_bf, float* __restrict__ out_f,
    const float* __restrict__ resid, int mode, int M)
{
    __shared__ float sC[32][196];        // stride 196: 16B-aligned rows, 2-way max bank alias
    int tid = threadIdx.x;
    int wave = tid >> 6;
    int lane = tid & 63;
    int rm_blk = blockIdx.x * 32;
    int rm = rm_blk + (wave >> 1) * 16;
    int half = wave & 1;
    int col = lane & 15;
    int quad = lane >> 4;

    if (rm < M) {
        int arow = rm + col;
        if (arow >= M) arow = M - 1;
        const u16* Ap = A + (size_t)arow * H + quad * 8;
        short8 a[6];
        #pragma unroll
        for (int k = 0; k < 6; k++) a[k] = *(const short8*)(Ap + k * 32);

        int lr = (wave >> 1) * 16 + quad * 4;
        int nb = half * 6;
        #pragma unroll
        for (int nt = 0; nt < 6; nt++) {
            int n = (nb + nt) * 16 + col;
            const u16* Bh = Wt_hi + (size_t)n * H + quad * 8;
            const u16* Bl = Wt_lo + (size_t)n * H + quad * 8;
            floatx4 c = {0.f, 0.f, 0.f, 0.f};
            #pragma unroll
            for (int k = 0; k < 6; k++) {
                short8 bh = *(const short8*)(Bh + k * 32);
                short8 bl = *(const short8*)(Bl + k * 32);
                c = __builtin_amdgcn_mfma_f32_16x16x32_bf16(a[k], bh, c, 0, 0, 0);
                c = __builtin_amdgcn_mfma_f32_16x16x32_bf16(a[k], bl, c, 0, 0, 0);
            }
            #pragma unroll
            for (int r = 0; r < 4; r++) sC[lr + r][n] = c[r];
        }
    }
    __syncthreads();

    int r = tid >> 3;                    // 0..31
    int c0 = (tid & 7) * 24;             // 24 contiguous cols
    int grow = rm_blk + r;
    if (grow >= M) return;
    float v[24];
    #pragma unroll
    for (int i = 0; i < 6; i++) {
        float4 q = *(const float4*)&sC[r][c0 + 4 * i];
        v[4*i+0] = q.x; v[4*i+1] = q.y; v[4*i+2] = q.z; v[4*i+3] = q.w;
    }
    #pragma unroll
    for (int i = 0; i < 6; i++) {
        float4 b = *(const float4*)&bias[c0 + 4 * i];
        v[4*i+0] = fmaxf(v[4*i+0] + b.x, 0.f);
        v[4*i+1] = fmaxf(v[4*i+1] + b.y, 0.f);
        v[4*i+2] = fmaxf(v[4*i+2] + b.z, 0.f);
        v[4*i+3] = fmaxf(v[4*i+3] + b.w, 0.f);
    }
    size_t o = (size_t)grow * H + c0;
    if (mode == 1) {
        #pragma unroll
        for (int i = 0; i < 6; i++) {
            float4 f = *(const float4*)&resid[o + 4 * i];
            f.x = (v[4*i+0] + f.x) * 0.5f;
            f.y = (v[4*i+1] + f.y) * 0.5f;
            f.z = (v[4*i+2] + f.z) * 0.5f;
            f.w = (v[4*i+3] + f.w) * 0.5f;
            v[4*i+0] = f.x; v[4*i+1] = f.y; v[4*i+2] = f.z; v[4*i+3] = f.w;
            *(float4*)&out_f[o + 4 * i] = f;
        }
    }
    #pragma unroll
    for (int i = 0; i < 3; i++) {
        uint4 p;
        p.x = pack2(v[8*i+0], v[8*i+1]);
        p.y = pack2(v[8*i+2], v[8*i+3]);
        p.z = pack2(v[8*i+4], v[8*i+5]);
        p.w = pack2(v[8*i+6], v[8*i+7]);
        *(uint4*)&out_bf[o + 8 * i] = p;
    }
}

// ---------------- Output head: coords = (adj@feats) @ W_out + b_out ----------------

__global__ void head_kernel(const u16* __restrict__ A, const float* __restrict__ W,
                            const float* __restrict__ b, float* __restrict__ coords, int M) {
    int row = blockIdx.x * blockDim.x + threadIdx.x;
    if (row >= M) return;
    float a0 = b[0], a1 = b[1], a2 = b[2];
    const u16* Ar = A + (size_t)row * H;
    for (int k = 0; k < H; k++) {
        float x = bf2f(Ar[k]);
        a0 += x * W[k * 3 + 0];
        a1 += x * W[k * 3 + 1];
        a2 += x * W[k * 3 + 2];
    }
    coords[row * 3 + 0] = a0;
    coords[row * 3 + 1] = a1;
    coords[row * 3 + 2] = a2;
}

// ---------------- Launch ----------------

extern "C" void kernel_launch(void* const* d_in, const int* in_sizes, int n_in,
                              void* d_out, int out_size, void* d_ws, size_t ws_size,
                              hipStream_t stream) {
    const float* features = (const float*)d_in[0];
    const int*   edge_src = (const int*)d_in[1];
    const int*   edge_dst = (const int*)d_in[2];
    const float* edge_w   = (const float*)d_in[3];
    const float* Ws       = (const float*)d_in[4];
    const float* bs       = (const float*)d_in[5];
    const float* W_out    = (const float*)d_in[6];
    const float* b_out    = (const float*)d_in[7];

    const int N = in_sizes[0] / H;
    const int E = in_sizes[1];

    float* coords = (float*)d_out;
    float* feats  = coords + (size_t)N * 3;   // fp32 feats output/accumulator

    char* wptr = (char*)d_ws;
    u16* xbuf_bf  = (u16*)wptr;   wptr += (size_t)N * H * sizeof(u16);
    u16* sup      = (u16*)wptr;   wptr += (size_t)N * H * sizeof(u16);
    u16* feats_bf = (u16*)wptr;   wptr += (size_t)N * H * sizeof(u16);
    u16* Wt_hi    = (u16*)wptr;   wptr += (size_t)NLAYER * HH * sizeof(u16);
    u16* Wt_lo    = (u16*)wptr;   wptr += (size_t)NLAYER * HH * sizeof(u16);
    int* counts   = (int*)wptr;   wptr += (size_t)N * sizeof(int);
    int* total    = (int*)wptr;   wptr += 4;                      // contiguous with counts
    int* rbeg     = (int*)wptr;   wptr += (size_t)N * sizeof(int);
    int* rcnt     = (int*)wptr;   wptr += (size_t)N * sizeof(int);
    int* cursor   = (int*)wptr;   wptr += (size_t)N * sizeof(int);
    int2* ce      = (int2*)wptr;  wptr += (size_t)E * sizeof(int2);

    // --- build CSR (dst-indexed, scan-free) ---
    hipMemsetAsync(counts, 0, (size_t)(N + 1) * sizeof(int), stream);  // counts + total
    hist_kernel<<<(E + 255) / 256, 256, 0, stream>>>(edge_dst, counts, E);
    alloc_kernel<<<(N + 255) / 256, 256, 0, stream>>>(counts, rbeg, rcnt, cursor, total, N);
    scatter_kernel<<<(E + 255) / 256, 256, 0, stream>>>(edge_src, edge_dst, edge_w,
                                                        cursor, ce, E);

    // --- weight split/transpose + feature conversion ---
    int wtotal = NLAYER * HH;
    wprep_kernel<<<(wtotal + 255) / 256, 256, 0, stream>>>(Ws, Wt_hi, Wt_lo, wtotal);
    int c4 = N * H / 4;
    conv_kernel<<<(c4 + 255) / 256, 256, 0, stream>>>(features, xbuf_bf, c4);

    int gblocks = (N + 31) / 32;
    int VC = (N + 23) / 24;

    // L0: agg = adj@f ; x0 = relu(agg W0 + b0)
    spmm_raw<<<VC, 192, 0, stream>>>(xbuf_bf, rbeg, rcnt, ce, sup, N);
    gemm_fused<<<gblocks, 256, 0, stream>>>(sup, Wt_hi + 0 * HH, Wt_lo + 0 * HH, bs + 0 * H,
                                            xbuf_bf, nullptr, nullptr, 0, N);
    // L1: agg = adj@x0 ; feats = (features + relu(agg W1 + b1))/2
    spmm_raw<<<VC, 192, 0, stream>>>(xbuf_bf, rbeg, rcnt, ce, sup, N);
    gemm_fused<<<gblocks, 256, 0, stream>>>(sup, Wt_hi + 1 * HH, Wt_lo + 1 * HH, bs + 1 * H,
                                            feats_bf, feats, features, 1, N);

    // blocks 2-6
    for (int i = 2; i < 12; i += 2) {
        spmm_raw<<<VC, 192, 0, stream>>>(feats_bf, rbeg, rcnt, ce, sup, N);
        gemm_fused<<<gblocks, 256, 0, stream>>>(sup, Wt_hi + (size_t)i * HH, Wt_lo + (size_t)i * HH,
                                                bs + (size_t)i * H, xbuf_bf, nullptr, nullptr, 0, N);
        spmm_raw<<<VC, 192, 0, stream>>>(xbuf_bf, rbeg, rcnt, ce, sup, N);
        gemm_fused<<<gblocks, 256, 0, stream>>>(sup, Wt_hi + (size_t)(i+1) * HH, Wt_lo + (size_t)(i+1) * HH,
                                                bs + (size_t)(i+1) * H, feats_bf, feats, feats, 1, N);
    }

    // gc13
    spmm_raw<<<VC, 192, 0, stream>>>(feats_bf, rbeg, rcnt, ce, sup, N);
    gemm_fused<<<gblocks, 256, 0, stream>>>(sup, Wt_hi + 12 * (size_t)HH, Wt_lo + 12 * (size_t)HH,
                                            bs + 12 * H, feats_bf, feats, feats, 1, N);

    // head: coords = (adj@feats) W_out + b_out
    spmm_raw<<<VC, 192, 0, stream>>>(feats_bf, rbeg, rcnt, ce, sup, N);
    head_kernel<<<(N + 255) / 256, 256, 0, stream>>>(sup, W_out, b_out, coords, N);
}